// Round 15
// baseline (956.623 us; speedup 1.0000x reference)
//
#include <hip/hip_runtime.h>
#include <hip/hip_bf16.h>

#define DI __device__ __forceinline__

typedef __attribute__((ext_vector_type(8))) short bf8;
typedef __attribute__((ext_vector_type(4))) float f4;
typedef __attribute__((ext_vector_type(8))) unsigned short us8;

#define LI    2048
#define LT    256
#define SEQ   2304
#define HID   3072
#define NHEAD 24
#define HD    128
#define N1    21504      // 3*HID + MLP
#define QKVW  9216       // 3*HID
#define N2CAT 15360      // HID + MLP

DI unsigned short f2bf(float f) {
  union { float f; unsigned u; } v; v.f = f;
  unsigned r = v.u + 0x7FFFu + ((v.u >> 16) & 1u);
  return (unsigned short)(r >> 16);
}
DI float bf2f(unsigned short h) {
  union { unsigned u; float f; } v; v.u = ((unsigned)h) << 16;
  return v.f;
}

DI void gload16(const void* g, void* l) {
  __builtin_amdgcn_global_load_lds(
      (const __attribute__((address_space(1))) void*)g,
      (__attribute__((address_space(3))) void*)l, 16, 0, 0);
}

DI f4 mfma16(bf8 a, bf8 b, f4 c) {
  return __builtin_amdgcn_mfma_f32_16x16x32_bf16(a, b, c, 0, 0, 0);
}

// ---------------- modulation GEMV: mod = silu(vec) @ mod_w^T + mod_b ----------------
__global__ void k_mod(const float* __restrict__ vec, const float* __restrict__ mw,
                      const float* __restrict__ mb, float* __restrict__ mod) {
  int row = blockIdx.x * 4 + (threadIdx.x >> 6);
  int lane = threadIdx.x & 63;
  const float4* wr = (const float4*)(mw + (size_t)row * HID);
  const float4* vv = (const float4*)vec;
  float s = 0.f;
  for (int i = lane; i < HID / 4; i += 64) {
    float4 w4 = wr[i], x4 = vv[i];
    s += (x4.x / (1.f + __expf(-x4.x))) * w4.x;
    s += (x4.y / (1.f + __expf(-x4.y))) * w4.y;
    s += (x4.z / (1.f + __expf(-x4.z))) * w4.z;
    s += (x4.w / (1.f + __expf(-x4.w))) * w4.w;
  }
#pragma unroll
  for (int m = 32; m; m >>= 1) s += __shfl_xor(s, m);
  if (lane == 0) mod[row] = s + mb[row];
}

// ---- layernorm+modulate (blocks 0..2303) + w1 f32->bf16 converter (blocks 2304..3327) ----
__global__ void k_lnmod(const float* __restrict__ img, const float* __restrict__ txt,
                        const float* __restrict__ mod, unsigned short* __restrict__ xmod,
                        const float* __restrict__ w1, unsigned short* __restrict__ w1b) {
  int t = blockIdx.x;
  if (t >= SEQ) {            // w1 converter
    int cb = t - SEQ;
    const int n4 = N1 * HID / 4;
    for (int i = cb * 256 + threadIdx.x; i < n4; i += 1024 * 256) {
      float4 f = ((const float4*)w1)[i];
      ushort4 o;
      o.x = f2bf(f.x); o.y = f2bf(f.y); o.z = f2bf(f.z); o.w = f2bf(f.w);
      ((ushort4*)w1b)[i] = o;
    }
    return;
  }
  const float* x = (t < LI) ? (img + (size_t)t * HID) : (txt + (size_t)(t - LI) * HID);
  const float4* x4 = (const float4*)x;
  float4 v[3];
  float s = 0.f, ss = 0.f;
#pragma unroll
  for (int j = 0; j < 3; ++j) {
    v[j] = x4[threadIdx.x + j * 256];
    s  += v[j].x + v[j].y + v[j].z + v[j].w;
    ss += v[j].x * v[j].x + v[j].y * v[j].y + v[j].z * v[j].z + v[j].w * v[j].w;
  }
#pragma unroll
  for (int m = 32; m; m >>= 1) { s += __shfl_xor(s, m); ss += __shfl_xor(ss, m); }
  __shared__ float red[8];
  int wv = threadIdx.x >> 6;
  if ((threadIdx.x & 63) == 0) { red[wv] = s; red[4 + wv] = ss; }
  __syncthreads();
  s = red[0] + red[1] + red[2] + red[3];
  ss = red[4] + red[5] + red[6] + red[7];
  float mu = s * (1.f / HID);
  float var = ss * (1.f / HID) - mu * mu;
  float inv = rsqrtf(var + 1e-6f);
  const float* shift = mod;
  const float* scale = mod + HID;
#pragma unroll
  for (int j = 0; j < 3; ++j) {
    int i = threadIdx.x + j * 256;
    int c = i * 4;
    ushort4 o;
    o.x = f2bf((v[j].x - mu) * inv * (1.f + scale[c + 0]) + shift[c + 0]);
    o.y = f2bf((v[j].y - mu) * inv * (1.f + scale[c + 1]) + shift[c + 1]);
    o.z = f2bf((v[j].z - mu) * inv * (1.f + scale[c + 2]) + shift[c + 2]);
    o.w = f2bf((v[j].w - mu) * inv * (1.f + scale[c + 3]) + shift[c + 3]);
    ((ushort4*)xmod)[(size_t)t * (HID / 4) + i] = o;
  }
}

#define BAR()    asm volatile("s_barrier" ::: "memory")
#define VMCNT6() asm volatile("s_waitcnt vmcnt(6)" ::: "memory")
#define VMCNT4() asm volatile("s_waitcnt vmcnt(4)" ::: "memory")
#define VMCNT2() asm volatile("s_waitcnt vmcnt(2)" ::: "memory")
#define VMCNT0() asm volatile("s_waitcnt vmcnt(0)" ::: "memory")
#define LGKM0()  do { asm volatile("s_waitcnt lgkmcnt(0)" ::: "memory"); \
                      __builtin_amdgcn_sched_barrier(0); } while (0)

// ===== GEMM1 (R12 core) + FUSED q/k RMSNorm+RoPE in epilogue =====
// bn<24 blocks hold complete heads (256 cols = 2 heads), all 256 rows; rope rows are
// block-uniform (LI = 8*256 -> bm<8). Norm on f32 acc (one fewer bf16 roundtrip).
__global__ __launch_bounds__(512, 2) void k_gemm1(const unsigned short* __restrict__ xmod,
    const unsigned short* __restrict__ w1b, const float* __restrict__ b1,
    unsigned short* __restrict__ qkv, unsigned short* __restrict__ amlp,
    const float* __restrict__ qnw, const float* __restrict__ knw,
    const float* __restrict__ fcos, const float* __restrict__ fsin) {
  __shared__ unsigned short As[2][256 * 64];
  __shared__ unsigned short Bs[2][256 * 64];
  const int K = HID;          // 3072
  const int NT = K / 64;      // 48 K-tiles
  int tid = threadIdx.x, lane = tid & 63, wid = tid >> 6;
  int wr = wid >> 2, wc = wid & 3;

  int b = blockIdx.x;
  const int Q = 756 / 8, R = 756 % 8;
  int xcd = b & 7, idx = b >> 3;
  int wg = (xcd < R ? xcd * (Q + 1) : R * (Q + 1) + (xcd - R) * Q) + idx;
  int bm = wg % 9, bn = wg / 9;

  const unsigned short* Ag = xmod + (size_t)bm * 256 * K;
  const unsigned short* Bg = w1b + (size_t)bn * 256 * K;

  int sgran = (lane & 7) ^ ((lane >> 3) & 7);
  int srow = wid * 16 + (lane >> 3);

#define STAGE_A(bufi, t, hh) do { \
    gload16(Ag + (size_t)((hh)*128 + srow) * K + (t)*64 + sgran*8, \
            &As[bufi][((hh)*128 + wid*16) * 64]); \
    gload16(Ag + (size_t)((hh)*128 + 8 + srow) * K + (t)*64 + sgran*8, \
            &As[bufi][((hh)*128 + wid*16 + 8) * 64]); \
  } while (0)
#define STAGE_B(bufi, t, hh) do { \
    gload16(Bg + (size_t)((hh)*128 + srow) * K + (t)*64 + sgran*8, \
            &Bs[bufi][((hh)*128 + wid*16) * 64]); \
    gload16(Bg + (size_t)((hh)*128 + 8 + srow) * K + (t)*64 + sgran*8, \
            &Bs[bufi][((hh)*128 + wid*16 + 8) * 64]); \
  } while (0)

  int rA = wr * 128 + (lane & 15);
  int rB = wc * 64 + (lane & 15);
  int qq = lane >> 4, l7 = lane & 7;

  f4 acc[8][4];
#pragma unroll
  for (int m = 0; m < 8; ++m)
#pragma unroll
    for (int n = 0; n < 4; ++n) acc[m][n] = (f4){0.f, 0.f, 0.f, 0.f};
  bf8 aL[4][2], aH[4][2], bL[2][2], bH[2][2];

#define RD(buf, r, s) (*(const bf8*)&buf[(r) * 64 + ((((s)*4 + qq) ^ l7) << 3)])

#define GROUP(C, tn, tn2) do { \
    _Pragma("unroll") for (int m = 0; m < 4; ++m) \
      _Pragma("unroll") for (int s = 0; s < 2; ++s) aL[m][s] = RD(As[C], rA + m*16, s); \
    _Pragma("unroll") for (int n = 0; n < 2; ++n) \
      _Pragma("unroll") for (int s = 0; s < 2; ++s) bL[n][s] = RD(Bs[C], rB + n*16, s); \
    STAGE_A(1-(C), tn, 1); STAGE_B(1-(C), tn, 0); STAGE_B(1-(C), tn, 1); \
    LGKM0(); \
    __builtin_amdgcn_s_setprio(1); \
    _Pragma("unroll") for (int m = 0; m < 4; ++m) \
      _Pragma("unroll") for (int n = 0; n < 2; ++n) \
        _Pragma("unroll") for (int s = 0; s < 2; ++s) \
          acc[m][n] = mfma16(aL[m][s], bL[n][s], acc[m][n]); \
    __builtin_amdgcn_s_setprio(0); \
    _Pragma("unroll") for (int n = 0; n < 2; ++n) \
      _Pragma("unroll") for (int s = 0; s < 2; ++s) bH[n][s] = RD(Bs[C], rB + (n+2)*16, s); \
    LGKM0(); \
    __builtin_amdgcn_s_setprio(1); \
    _Pragma("unroll") for (int m = 0; m < 4; ++m) \
      _Pragma("unroll") for (int n = 0; n < 2; ++n) \
        _Pragma("unroll") for (int s = 0; s < 2; ++s) \
          acc[m][n+2] = mfma16(aL[m][s], bH[n][s], acc[m][n+2]); \
    __builtin_amdgcn_s_setprio(0); \
    _Pragma("unroll") for (int m = 0; m < 4; ++m) \
      _Pragma("unroll") for (int s = 0; s < 2; ++s) aH[m][s] = RD(As[C], rA + (m+4)*16, s); \
    LGKM0(); \
    BAR(); \
    __builtin_amdgcn_s_setprio(1); \
    _Pragma("unroll") for (int m = 0; m < 4; ++m) \
      _Pragma("unroll") for (int n = 0; n < 2; ++n) \
        _Pragma("unroll") for (int s = 0; s < 2; ++s) \
          acc[m+4][n+2] = mfma16(aH[m][s], bH[n][s], acc[m+4][n+2]); \
    __builtin_amdgcn_s_setprio(0); \
    STAGE_A(C, tn2, 0); \
    __builtin_amdgcn_s_setprio(1); \
    _Pragma("unroll") for (int m = 0; m < 4; ++m) \
      _Pragma("unroll") for (int n = 0; n < 2; ++n) \
        _Pragma("unroll") for (int s = 0; s < 2; ++s) \
          acc[m+4][n] = mfma16(aH[m][s], bL[n][s], acc[m+4][n]); \
    __builtin_amdgcn_s_setprio(0); \
    VMCNT2(); \
    BAR(); \
  } while (0)

  STAGE_A(0, 0, 0); STAGE_A(0, 0, 1); STAGE_B(0, 0, 0); STAGE_B(0, 0, 1);
  STAGE_A(1, 1, 0);
  VMCNT2();
  BAR();

  for (int i = 0; i < NT / 2; ++i) {
    int t0 = 2 * i;
    int n1 = t0 + 2; if (n1 > NT - 1) n1 = NT - 1;
    int n2 = t0 + 3; if (n2 > NT - 1) n2 = NT - 1;
    GROUP(0, t0 + 1, n1);
    GROUP(1, n1, n2);
  }
  VMCNT0();

  int r0 = bm * 256 + wr * 128 + ((lane >> 4) << 2);
  int c0 = bn * 256 + wc * 64 + (lane & 15);
  if (bn < 24) {
    // --- fused RMSNorm (+RoPE for img rows) on q/k ---
    const float* wqk = (bn < 12) ? qnw : knw;
    bool dorope = (bm < 8);          // rows < 2048 iff bm < 8 (block-uniform)
#pragma unroll
    for (int n = 0; n < 4; ++n) {
      float bias = b1[c0 + n * 16];
#pragma unroll
      for (int m = 0; m < 8; ++m)
#pragma unroll
        for (int j = 0; j < 4; ++j) acc[m][n][j] += bias;
    }
    float ssv[8][4];
#pragma unroll
    for (int m = 0; m < 8; ++m)
#pragma unroll
      for (int j = 0; j < 4; ++j) {
        float s = 0.f;
#pragma unroll
        for (int n = 0; n < 4; ++n) s += acc[m][n][j] * acc[m][n][j];
#pragma unroll
        for (int mk = 8; mk; mk >>= 1) s += __shfl_xor(s, mk);  // 16-lane butterfly
        ssv[m][j] = s;
      }
    float* sred = (float*)&As[0][0];   // 4 KB scratch (LDS idle after main loop)
    BAR();
    if ((lane & 15) == 0) {
      int g = lane >> 4;
#pragma unroll
      for (int m = 0; m < 8; ++m)
#pragma unroll
        for (int j = 0; j < 4; ++j)
          sred[wid * 128 + m * 16 + g * 4 + j] = ssv[m][j];
    }
    BAR();
    int dbase = (wc & 1) * 64 + (lane & 15);   // within-head dim
#pragma unroll
    for (int m = 0; m < 8; ++m) {
#pragma unroll
      for (int j = 0; j < 4; ++j) {
        float tot = ssv[m][j] + sred[(wid ^ 1) * 128 + m * 16 + (lane >> 4) * 4 + j];
        float inv = rsqrtf(tot * (1.f / HD) + 1e-6f);
        int row = r0 + m * 16 + j;
#pragma unroll
        for (int n = 0; n < 4; ++n) {
          int d = dbase + n * 16;
          float y = acc[m][n][j] * inv * wqk[d];
          float yp = __shfl_xor(y, 1);     // RoPE partner (d^1 lives in lane^1)
          if (dorope) {
            float cc = fcos[row * HD + d], sn = fsin[row * HD + d];
            y = (d & 1) ? (y * cc + yp * sn) : (y * cc - yp * sn);
          }
          qkv[(size_t)row * QKVW + (c0 + n * 16)] = f2bf(y);
        }
      }
    }
  } else {
    bool isv = (bn < 36);
#pragma unroll
    for (int m = 0; m < 8; ++m) {
#pragma unroll
      for (int n = 0; n < 4; ++n) {
        int col = c0 + n * 16;
        float bias = b1[col];
#pragma unroll
        for (int j = 0; j < 4; ++j) {
          int row = r0 + m * 16 + j;
          float v = acc[m][n][j] + bias;
          if (isv) {
            qkv[(size_t)row * QKVW + col] = f2bf(v);
          } else {
            float u = 0.7978845608f * (v + 0.044715f * v * v * v);
            float g = v / (1.f + __expf(-2.f * u));
            amlp[(size_t)row * N2CAT + (col - 6144)] = f2bf(g);
          }
        }
      }
    }
  }
#undef STAGE_A
#undef STAGE_B
#undef RD
#undef GROUP
}

// ===== GEMM2 (R12 verbatim): 256x128, BK=64, 3-ring, 4-bar =====
__global__ __launch_bounds__(512, 2) void k_gemm2(const unsigned short* __restrict__ amlp,
    const unsigned short* __restrict__ w2b, const float* __restrict__ b2,
    const float* __restrict__ img, const float* __restrict__ txt,
    const float* __restrict__ gate, float* __restrict__ out) {
  __shared__ unsigned short As[3][256 * 64];
  __shared__ unsigned short Bs[3][128 * 64];
  const int K = N2CAT;        // 15360
  const int NT = K / 64;      // 240 K-tiles
  int tid = threadIdx.x, lane = tid & 63, wid = tid >> 6;
  int wr = wid >> 1, wc = wid & 1;

  int b = blockIdx.x;                       // 216 % 8 == 0
  int bsw = (b & 7) * 27 + (b >> 3);
  int bm = bsw % 9, bn = bsw / 9;

  const unsigned short* Ag = amlp + (size_t)bm * 256 * K;
  const unsigned short* Bg = w2b + (size_t)bn * 128 * K;

  int sgran = (lane & 7) ^ ((lane >> 3) & 7);
  int srow = wid * 16 + (lane >> 3);

#define STAGE2_A(bufi, t, hh) do { \
    gload16(Ag + (size_t)((hh)*128 + srow) * K + (t)*64 + sgran*8, \
            &As[bufi][((hh)*128 + wid*16) * 64]); \
    gload16(Ag + (size_t)((hh)*128 + 8 + srow) * K + (t)*64 + sgran*8, \
            &As[bufi][((hh)*128 + wid*16 + 8) * 64]); \
  } while (0)
#define STAGE2_B(bufi, t) do { \
    gload16(Bg + (size_t)(srow) * K + (t)*64 + sgran*8, \
            &Bs[bufi][(wid*16) * 64]); \
    gload16(Bg + (size_t)(8 + srow) * K + (t)*64 + sgran*8, \
            &Bs[bufi][(wid*16 + 8) * 64]); \
  } while (0)

  int rA = wr * 64 + (lane & 15);
  int rB = wc * 64 + (lane & 15);
  int qq = lane >> 4, l7 = lane & 7;

  f4 acc[4][4];
#pragma unroll
  for (int m = 0; m < 4; ++m)
#pragma unroll
    for (int n = 0; n < 4; ++n) acc[m][n] = (f4){0.f, 0.f, 0.f, 0.f};
  bf8 aL[2][2], aH[2][2], bL[2][2], bH[2][2];

#define RD2(buf, r, s) (*(const bf8*)&buf[(r) * 64 + ((((s)*4 + qq) ^ l7) << 3)])

#define GROUP2(C, SB, t, full) do { \
    _Pragma("unroll") for (int m = 0; m < 2; ++m) \
      _Pragma("unroll") for (int s = 0; s < 2; ++s) aL[m][s] = RD2(As[C], rA + m*16, s); \
    _Pragma("unroll") for (int n = 0; n < 2; ++n) \
      _Pragma("unroll") for (int s = 0; s < 2; ++s) bL[n][s] = RD2(Bs[C], rB + n*16, s); \
    if (full) STAGE2_A(SB, (t) + 2, 0); \
    LGKM0(); \
    __builtin_amdgcn_s_setprio(1); \
    _Pragma("unroll") for (int m = 0; m < 2; ++m) \
      _Pragma("unroll") for (int n = 0; n < 2; ++n) \
        _Pragma("unroll") for (int s = 0; s < 2; ++s) \
          acc[m][n] = mfma16(aL[m][s], bL[n][s], acc[m][n]); \
    __builtin_amdgcn_s_setprio(0); \
    BAR(); \
    _Pragma("unroll") for (int n = 0; n < 2; ++n) \
      _Pragma("unroll") for (int s = 0; s < 2; ++s) bH[n][s] = RD2(Bs[C], rB + (n+2)*16, s); \
    if (full) STAGE2_A(SB, (t) + 2, 1); \
    LGKM0(); \
    __builtin_amdgcn_s_setprio(1); \
    _Pragma("unroll") for (int m = 0; m < 2; ++m) \
      _Pragma("unroll") for (int n = 0; n < 2; ++n) \
        _Pragma("unroll") for (int s = 0; s < 2; ++s) \
          acc[m][n+2] = mfma16(aL[m][s], bH[n][s], acc[m][n+2]); \
    __builtin_amdgcn_s_setprio(0); \
    BAR(); \
    _Pragma("unroll") for (int m = 0; m < 2; ++m) \
      _Pragma("unroll") for (int s = 0; s < 2; ++s) aH[m][s] = RD2(As[C], rA + (m+2)*16, s); \
    if (full) STAGE2_B(SB, (t) + 2); \
    LGKM0(); \
    __builtin_amdgcn_s_setprio(1); \
    _Pragma("unroll") for (int m = 0; m < 2; ++m) \
      _Pragma("unroll") for (int n = 0; n < 2; ++n) \
        _Pragma("unroll") for (int s = 0; s < 2; ++s) \
          acc[m+2][n+2] = mfma16(aH[m][s], bH[n][s], acc[m+2][n+2]); \
    __builtin_amdgcn_s_setprio(0); \
    BAR(); \
    __builtin_amdgcn_s_setprio(1); \
    _Pragma("unroll") for (int m = 0; m < 2; ++m) \
      _Pragma("unroll") for (int n = 0; n < 2; ++n) \
        _Pragma("unroll") for (int s = 0; s < 2; ++s) \
          acc[m+2][n] = mfma16(aH[m][s], bL[n][s], acc[m+2][n]); \
    __builtin_amdgcn_s_setprio(0); \
    if (full) { VMCNT6(); } else { VMCNT0(); } \
    BAR(); \
  } while (0)

  STAGE2_A(0, 0, 0); STAGE2_A(0, 0, 1); STAGE2_B(0, 0);
  STAGE2_A(1, 1, 0); STAGE2_A(1, 1, 1); STAGE2_B(1, 1);
  VMCNT6();
  BAR();

  for (int i = 0; i < NT / 3; ++i) {
    int t = 3 * i;
    GROUP2(0, 2, t,     (t + 2) < NT);
    GROUP2(1, 0, t + 1, (t + 3) < NT);
    GROUP2(2, 1, t + 2, (t + 4) < NT);
  }
  VMCNT0();

  int r0 = bm * 256 + wr * 64 + ((lane >> 4) << 2);
  int c0 = bn * 128 + wc * 64 + (lane & 15);
#pragma unroll
  for (int m = 0; m < 4; ++m) {
#pragma unroll
    for (int n = 0; n < 4; ++n) {
      int col = c0 + n * 16;
      float bias = b2[col];
      float gt = gate[col];
#pragma unroll
      for (int j = 0; j < 4; ++j) {
        int row = r0 + m * 16 + j;
        float v = acc[m][n][j] + bias;
        float res = (row < LI) ? img[(size_t)row * HID + col]
                               : txt[(size_t)(row - LI) * HID + col];
        out[(size_t)row * HID + col] = res + gt * v;
      }
    }
  }
#undef STAGE2_A
#undef STAGE2_B
#undef RD2
#undef GROUP2
}

// ---------------- transpose V only: qkv v-slice [S][24*128] -> vt [24][128][S] ----------------
__global__ void k_vt(const unsigned short* __restrict__ qkv, unsigned short* __restrict__ vt) {
  int b = blockIdx.x;                 // 24*36*2 = 1728
  int tid = threadIdx.x;
  __shared__ unsigned short tile[64 * 65];
  int h = b / 72; int rem = b - h * 72; int tt = rem >> 1; int dd = rem & 1;
  int t0 = tt * 64, d0 = dd * 64;
#pragma unroll
  for (int j = 0; j < 2; ++j) {
    int idx = j * 256 + tid;
    int row = idx >> 3, s = idx & 7;
    us8 vv = *(const us8*)(qkv + (size_t)(t0 + row) * QKVW + 2 * HID + h * HD + d0 + s * 8);
#pragma unroll
    for (int i = 0; i < 8; ++i) tile[row * 65 + s * 8 + i] = vv[i];
  }
  __syncthreads();
#pragma unroll
  for (int j = 0; j < 2; ++j) {
    int idx = j * 256 + tid;
    int dr = idx >> 3, sl = idx & 7;
    us8 o;
#pragma unroll
    for (int i = 0; i < 8; ++i) o[i] = tile[(sl * 8 + i) * 65 + dr];
    *(us8*)(vt + (size_t)(h * HD + d0 + dr) * SEQ + t0 + sl * 8) = o;
  }
}

// ===== flash attention v3 (R12 verbatim): QBLK=128, 8 waves, K/V dbuf, Q-frags global =====
__global__ __launch_bounds__(512, 4) void k_attn(const unsigned short* __restrict__ qkv,
                                                 const unsigned short* __restrict__ vt,
                                                 unsigned short* __restrict__ amlp,
                                                 const float* __restrict__ w2,
                                                 unsigned short* __restrict__ w2b) {
  int b = blockIdx.x;
  int tid = threadIdx.x;
  if (b >= 432) {           // w2 converter blocks
    int cb = b - 432;
    const int n4 = HID * N2CAT / 4;
    for (int i = cb * 512 + tid; i < n4; i += 768 * 512) {
      float4 f = ((const float4*)w2)[i];
      ushort4 o;
      o.x = f2bf(f.x); o.y = f2bf(f.y); o.z = f2bf(f.z); o.w = f2bf(f.w);
      ((ushort4*)w2b)[i] = o;
    }
    return;
  }
  __shared__ unsigned short S[40960];   // 80 KB
  unsigned short* Ks = S;               // 2 x 8192 (64x128)
  unsigned short* Vs = S + 16384;       // 2 x 8192 (128x64)
  unsigned short* Ps = S + 32768;       // 128 x 64

  int bsw = (b & 7) * 54 + (b >> 3);    // 432 = 54*8
  int head = bsw / 18, qt = bsw - head * 18;
  int lane = tid & 63, wv = tid >> 6;
  int qbase = qt * 128;

#define STAGEK(dst, t) do { \
    int rl_ = tid >> 4, sl_ = tid & 15, sg_ = sl_ ^ (rl_ & 7); \
    const unsigned short* kg_ = qkv + HID + (size_t)((t) * 64 + rl_) * QKVW + head * HD + sg_ * 8; \
    gload16(kg_, &(dst)[tid * 8]); \
    gload16(kg_ + (size_t)32 * QKVW, &(dst)[(512 + tid) * 8]); \
  } while (0)
#define STAGEV(dst, t) do { \
    int rl_ = tid >> 3, sl_ = tid & 7, sg_ = sl_ ^ (rl_ & 7); \
    const unsigned short* vg_ = vt + (size_t)(head * HD + rl_) * SEQ + (t) * 64 + sg_ * 8; \
    gload16(vg_, &(dst)[tid * 8]); \
    gload16(vg_ + (size_t)64 * SEQ, &(dst)[(512 + tid) * 8]); \
  } while (0)

  bf8 qf[4];
  {
    const unsigned short* qp =
        qkv + (size_t)(qbase + wv * 16 + (lane & 15)) * QKVW + head * HD + (lane >> 4) * 8;
#pragma unroll
    for (int kk = 0; kk < 4; ++kk) qf[kk] = *(const bf8*)(qp + kk * 32);
  }
  STAGEK(Ks, 0); STAGEV(Vs, 0);
  STAGEK(Ks + 8192, 1); STAGEV(Vs + 8192, 1);
  VMCNT4();
  BAR();

  float mrun[4], lrun[4];
  f4 oacc[8];
#pragma unroll
  for (int j = 0; j < 4; ++j) { mrun[j] = -1e30f; lrun[j] = 0.f; }
#pragma unroll
  for (int n = 0; n < 8; ++n) oacc[n] = (f4){0.f, 0.f, 0.f, 0.f};

  for (int kt = 0; kt < SEQ / 64; ++kt) {
    int cur = kt & 1;
    const unsigned short* Kc = Ks + cur * 8192;
    const unsigned short* Vc = Vs + cur * 8192;
    f4 sacc[4];
#pragma unroll
    for (int n = 0; n < 4; ++n) sacc[n] = (f4){0.f, 0.f, 0.f, 0.f};
#pragma unroll
    for (int kk = 0; kk < 4; ++kk) {
#pragma unroll
      for (int n = 0; n < 4; ++n) {
        int row = n * 16 + (lane & 15);
        int col = (kk * 32 + ((lane >> 4) * 8)) ^ ((lane & 7) << 3);
        bf8 kf = *(const bf8*)&Kc[row * 128 + col];
        sacc[n] = mfma16(qf[kk], kf, sacc[n]);
      }
    }
    const float SC = 0.08838834764831845f;
    float mj[4];
#pragma unroll
    for (int j = 0; j < 4; ++j)
      mj[j] = fmaxf(fmaxf(sacc[0][j], sacc[1][j]), fmaxf(sacc[2][j], sacc[3][j]));
#pragma unroll
    for (int j = 0; j < 4; ++j) {
#pragma unroll
      for (int mk = 8; mk; mk >>= 1) mj[j] = fmaxf(mj[j], __shfl_xor(mj[j], mk));
    }
    float resc[4], psum[4];
#pragma unroll
    for (int j = 0; j < 4; ++j) {
      float nm = fmaxf(mrun[j], mj[j] * SC);
      resc[j] = __expf(mrun[j] - nm);
      mrun[j] = nm;
      psum[j] = 0.f;
    }
#pragma unroll
    for (int n = 0; n < 4; ++n) {
#pragma unroll
      for (int j = 0; j < 4; ++j) {
        float p = __expf(sacc[n][j] * SC - mrun[j]);
        psum[j] += p;
        int row = wv * 16 + ((lane >> 4) << 2) + j;
        int col = (n * 16 + (lane & 15)) ^ ((row & 7) << 3);
        Ps[row * 64 + col] = f2bf(p);
      }
    }
#pragma unroll
    for (int j = 0; j < 4; ++j) {
#pragma unroll
      for (int mk = 8; mk; mk >>= 1) psum[j] += __shfl_xor(psum[j], mk);
      lrun[j] = lrun[j] * resc[j] + psum[j];
    }
#pragma unroll
    for (int n = 0; n < 8; ++n) {
#pragma unroll
      for (int j = 0; j < 4; ++j) oacc[n][j] *= resc[j];
    }
#pragma unroll
    for (int kk = 0; kk < 2; ++kk) {
      int prow = wv * 16 + (lane & 15);
      int pcol = (kk * 32 + ((lane >> 4) * 8)) ^ ((lane & 7) << 3);
      bf8 pa = *(const bf8*)&Ps[prow * 64 + pcol];
#pragma unroll
      for (int n = 0; n < 8; ++n) {
        int vrow = n * 16 + (lane & 15);
        int vcol = (kk * 32 + ((lane >> 4) * 8)) ^ ((vrow & 7) << 3);
        bf8 vf = *(const bf8*)&Vc[vrow * 64 + vcol];
        oacc[n] = mfma16(pa, vf, oacc[n]);
      }
    }
    BAR();
    if (kt + 2 < SEQ / 64) {
      STAGEK(Ks + cur * 8192, kt + 2);
      STAGEV(Vs + cur * 8192, kt + 2);
      VMCNT4();
    } else {
      VMCNT0();
    }
    BAR();
  }
#undef STAGEK
#undef STAGEV

#pragma unroll
  for (int j = 0; j < 4; ++j) {
    float invl = 1.f / lrun[j];
    int row = qbase + wv * 16 + ((lane >> 4) << 2) + j;
#pragma unroll
    for (int n = 0; n < 8; ++n) {
      int col = head * HD + n * 16 + (lane & 15);
      amlp[(size_t)row * N2CAT + col] = f2bf(oacc[n][j] * invl);
    }
  }
}

extern "C" void kernel_launch(void* const* d_in, const int* in_sizes, int n_in,
                              void* d_out, int out_size, void* d_ws, size_t ws_size,
                              hipStream_t stream) {
  (void)in_sizes; (void)n_in; (void)out_size; (void)ws_size;
  const float* img  = (const float*)d_in[0];
  const float* txt  = (const float*)d_in[1];
  const float* vec  = (const float*)d_in[2];
  const float* fcos = (const float*)d_in[3];
  const float* fsin = (const float*)d_in[4];
  const float* w1   = (const float*)d_in[5];
  const float* b1   = (const float*)d_in[6];
  const float* w2   = (const float*)d_in[7];
  const float* b2   = (const float*)d_in[8];
  const float* qnw  = (const float*)d_in[9];
  const float* knw  = (const float*)d_in[10];
  const float* mw   = (const float*)d_in[11];
  const float* mb   = (const float*)d_in[12];
  float* out = (float*)d_out;

  char* ws = (char*)d_ws;
  float*          mod  = (float*)(ws);                          // 36,864 B
  unsigned short* xmod = (unsigned short*)(ws + 40960);         // 14,155,776 B
  unsigned short* w1b  = (unsigned short*)(ws + 14196736);      // 132,120,576 B
  unsigned short* qkv  = (unsigned short*)(ws + 146317312);     // 42,467,328 B
  unsigned short* amlp = (unsigned short*)(ws + 188784640);     // 70,778,880 B (end ~259.6MB)
  unsigned short* vtb  = xmod;   // x_mod dead after GEMM1
  unsigned short* w2b  = w1b;    // w1 bf16 dead after GEMM1 (w2 converted inside k_attn)

  k_mod<<<QKVW / 4, 256, 0, stream>>>(vec, mw, mb, mod);
  k_lnmod<<<SEQ + 1024, 256, 0, stream>>>(img, txt, mod, xmod, w1, w1b);
  k_gemm1<<<756, 512, 0, stream>>>(xmod, w1b, b1, qkv, amlp, qnw, knw, fcos, fsin);
  k_vt<<<NHEAD * 36 * 2, 256, 0, stream>>>(qkv, vtb);
  k_attn<<<432 + 768, 512, 0, stream>>>(qkv, vtb, amlp, w2, w2b);
  k_gemm2<<<216, 512, 0, stream>>>(amlp, w2b, b2, img, txt, mod + 2 * HID, out);
}

// Round 16
// 873.433 us; speedup vs baseline: 1.0952x; 1.0952x over previous
//
#include <hip/hip_runtime.h>
#include <hip/hip_bf16.h>

#define DI __device__ __forceinline__

typedef __attribute__((ext_vector_type(8))) short bf8;
typedef __attribute__((ext_vector_type(4))) float f4;
typedef __attribute__((ext_vector_type(8))) unsigned short us8;

#define LI    2048
#define LT    256
#define SEQ   2304
#define HID   3072
#define NHEAD 24
#define HD    128
#define N1    21504      // 3*HID + MLP
#define QKVW  9216       // 3*HID
#define N2CAT 15360      // HID + MLP

DI unsigned short f2bf(float f) {
  union { float f; unsigned u; } v; v.f = f;
  unsigned r = v.u + 0x7FFFu + ((v.u >> 16) & 1u);
  return (unsigned short)(r >> 16);
}
DI float bf2f(unsigned short h) {
  union { unsigned u; float f; } v; v.u = ((unsigned)h) << 16;
  return v.f;
}

DI void gload16(const void* g, void* l) {
  __builtin_amdgcn_global_load_lds(
      (const __attribute__((address_space(1))) void*)g,
      (__attribute__((address_space(3))) void*)l, 16, 0, 0);
}

DI f4 mfma16(bf8 a, bf8 b, f4 c) {
  return __builtin_amdgcn_mfma_f32_16x16x32_bf16(a, b, c, 0, 0, 0);
}

// ---------------- modulation GEMV: mod = silu(vec) @ mod_w^T + mod_b ----------------
__global__ void k_mod(const float* __restrict__ vec, const float* __restrict__ mw,
                      const float* __restrict__ mb, float* __restrict__ mod) {
  int row = blockIdx.x * 4 + (threadIdx.x >> 6);
  int lane = threadIdx.x & 63;
  const float4* wr = (const float4*)(mw + (size_t)row * HID);
  const float4* vv = (const float4*)vec;
  float s = 0.f;
  for (int i = lane; i < HID / 4; i += 64) {
    float4 w4 = wr[i], x4 = vv[i];
    s += (x4.x / (1.f + __expf(-x4.x))) * w4.x;
    s += (x4.y / (1.f + __expf(-x4.y))) * w4.y;
    s += (x4.z / (1.f + __expf(-x4.z))) * w4.z;
    s += (x4.w / (1.f + __expf(-x4.w))) * w4.w;
  }
#pragma unroll
  for (int m = 32; m; m >>= 1) s += __shfl_xor(s, m);
  if (lane == 0) mod[row] = s + mb[row];
}

// ---- layernorm+modulate (blocks 0..2303) + w1 f32->bf16 converter (blocks 2304..3327) ----
__global__ void k_lnmod(const float* __restrict__ img, const float* __restrict__ txt,
                        const float* __restrict__ mod, unsigned short* __restrict__ xmod,
                        const float* __restrict__ w1, unsigned short* __restrict__ w1b) {
  int t = blockIdx.x;
  if (t >= SEQ) {            // w1 converter
    int cb = t - SEQ;
    const int n4 = N1 * HID / 4;
    for (int i = cb * 256 + threadIdx.x; i < n4; i += 1024 * 256) {
      float4 f = ((const float4*)w1)[i];
      ushort4 o;
      o.x = f2bf(f.x); o.y = f2bf(f.y); o.z = f2bf(f.z); o.w = f2bf(f.w);
      ((ushort4*)w1b)[i] = o;
    }
    return;
  }
  const float* x = (t < LI) ? (img + (size_t)t * HID) : (txt + (size_t)(t - LI) * HID);
  const float4* x4 = (const float4*)x;
  float4 v[3];
  float s = 0.f, ss = 0.f;
#pragma unroll
  for (int j = 0; j < 3; ++j) {
    v[j] = x4[threadIdx.x + j * 256];
    s  += v[j].x + v[j].y + v[j].z + v[j].w;
    ss += v[j].x * v[j].x + v[j].y * v[j].y + v[j].z * v[j].z + v[j].w * v[j].w;
  }
#pragma unroll
  for (int m = 32; m; m >>= 1) { s += __shfl_xor(s, m); ss += __shfl_xor(ss, m); }
  __shared__ float red[8];
  int wv = threadIdx.x >> 6;
  if ((threadIdx.x & 63) == 0) { red[wv] = s; red[4 + wv] = ss; }
  __syncthreads();
  s = red[0] + red[1] + red[2] + red[3];
  ss = red[4] + red[5] + red[6] + red[7];
  float mu = s * (1.f / HID);
  float var = ss * (1.f / HID) - mu * mu;
  float inv = rsqrtf(var + 1e-6f);
  const float* shift = mod;
  const float* scale = mod + HID;
#pragma unroll
  for (int j = 0; j < 3; ++j) {
    int i = threadIdx.x + j * 256;
    int c = i * 4;
    ushort4 o;
    o.x = f2bf((v[j].x - mu) * inv * (1.f + scale[c + 0]) + shift[c + 0]);
    o.y = f2bf((v[j].y - mu) * inv * (1.f + scale[c + 1]) + shift[c + 1]);
    o.z = f2bf((v[j].z - mu) * inv * (1.f + scale[c + 2]) + shift[c + 2]);
    o.w = f2bf((v[j].w - mu) * inv * (1.f + scale[c + 3]) + shift[c + 3]);
    ((ushort4*)xmod)[(size_t)t * (HID / 4) + i] = o;
  }
}

#define BAR()    asm volatile("s_barrier" ::: "memory")
#define VMCNT6() asm volatile("s_waitcnt vmcnt(6)" ::: "memory")
#define VMCNT4() asm volatile("s_waitcnt vmcnt(4)" ::: "memory")
#define VMCNT2() asm volatile("s_waitcnt vmcnt(2)" ::: "memory")
#define VMCNT0() asm volatile("s_waitcnt vmcnt(0)" ::: "memory")
#define LGKM0()  do { asm volatile("s_waitcnt lgkmcnt(0)" ::: "memory"); \
                      __builtin_amdgcn_sched_barrier(0); } while (0)

// ===== GEMM1 (R12 measured-best, 328us): 256x256, BK=64, 8-wave, 2 bar/K-tile =====
__global__ __launch_bounds__(512, 2) void k_gemm1(const unsigned short* __restrict__ xmod,
    const unsigned short* __restrict__ w1b, const float* __restrict__ b1,
    unsigned short* __restrict__ qkv, unsigned short* __restrict__ amlp) {
  __shared__ unsigned short As[2][256 * 64];
  __shared__ unsigned short Bs[2][256 * 64];
  const int K = HID;          // 3072
  const int NT = K / 64;      // 48 K-tiles
  int tid = threadIdx.x, lane = tid & 63, wid = tid >> 6;
  int wr = wid >> 2, wc = wid & 3;

  int b = blockIdx.x;
  const int Q = 756 / 8, R = 756 % 8;
  int xcd = b & 7, idx = b >> 3;
  int wg = (xcd < R ? xcd * (Q + 1) : R * (Q + 1) + (xcd - R) * Q) + idx;
  int bm = wg % 9, bn = wg / 9;

  const unsigned short* Ag = xmod + (size_t)bm * 256 * K;
  const unsigned short* Bg = w1b + (size_t)bn * 256 * K;

  int sgran = (lane & 7) ^ ((lane >> 3) & 7);
  int srow = wid * 16 + (lane >> 3);

#define STAGE_A(bufi, t, hh) do { \
    gload16(Ag + (size_t)((hh)*128 + srow) * K + (t)*64 + sgran*8, \
            &As[bufi][((hh)*128 + wid*16) * 64]); \
    gload16(Ag + (size_t)((hh)*128 + 8 + srow) * K + (t)*64 + sgran*8, \
            &As[bufi][((hh)*128 + wid*16 + 8) * 64]); \
  } while (0)
#define STAGE_B(bufi, t, hh) do { \
    gload16(Bg + (size_t)((hh)*128 + srow) * K + (t)*64 + sgran*8, \
            &Bs[bufi][((hh)*128 + wid*16) * 64]); \
    gload16(Bg + (size_t)((hh)*128 + 8 + srow) * K + (t)*64 + sgran*8, \
            &Bs[bufi][((hh)*128 + wid*16 + 8) * 64]); \
  } while (0)

  int rA = wr * 128 + (lane & 15);
  int rB = wc * 64 + (lane & 15);
  int qq = lane >> 4, l7 = lane & 7;

  f4 acc[8][4];
#pragma unroll
  for (int m = 0; m < 8; ++m)
#pragma unroll
    for (int n = 0; n < 4; ++n) acc[m][n] = (f4){0.f, 0.f, 0.f, 0.f};
  bf8 aL[4][2], aH[4][2], bL[2][2], bH[2][2];

#define RD(buf, r, s) (*(const bf8*)&buf[(r) * 64 + ((((s)*4 + qq) ^ l7) << 3)])

#define GROUP(C, tn, tn2) do { \
    _Pragma("unroll") for (int m = 0; m < 4; ++m) \
      _Pragma("unroll") for (int s = 0; s < 2; ++s) aL[m][s] = RD(As[C], rA + m*16, s); \
    _Pragma("unroll") for (int n = 0; n < 2; ++n) \
      _Pragma("unroll") for (int s = 0; s < 2; ++s) bL[n][s] = RD(Bs[C], rB + n*16, s); \
    STAGE_A(1-(C), tn, 1); STAGE_B(1-(C), tn, 0); STAGE_B(1-(C), tn, 1); \
    LGKM0(); \
    __builtin_amdgcn_s_setprio(1); \
    _Pragma("unroll") for (int m = 0; m < 4; ++m) \
      _Pragma("unroll") for (int n = 0; n < 2; ++n) \
        _Pragma("unroll") for (int s = 0; s < 2; ++s) \
          acc[m][n] = mfma16(aL[m][s], bL[n][s], acc[m][n]); \
    __builtin_amdgcn_s_setprio(0); \
    _Pragma("unroll") for (int n = 0; n < 2; ++n) \
      _Pragma("unroll") for (int s = 0; s < 2; ++s) bH[n][s] = RD(Bs[C], rB + (n+2)*16, s); \
    LGKM0(); \
    __builtin_amdgcn_s_setprio(1); \
    _Pragma("unroll") for (int m = 0; m < 4; ++m) \
      _Pragma("unroll") for (int n = 0; n < 2; ++n) \
        _Pragma("unroll") for (int s = 0; s < 2; ++s) \
          acc[m][n+2] = mfma16(aL[m][s], bH[n][s], acc[m][n+2]); \
    __builtin_amdgcn_s_setprio(0); \
    _Pragma("unroll") for (int m = 0; m < 4; ++m) \
      _Pragma("unroll") for (int s = 0; s < 2; ++s) aH[m][s] = RD(As[C], rA + (m+4)*16, s); \
    LGKM0(); \
    BAR(); \
    __builtin_amdgcn_s_setprio(1); \
    _Pragma("unroll") for (int m = 0; m < 4; ++m) \
      _Pragma("unroll") for (int n = 0; n < 2; ++n) \
        _Pragma("unroll") for (int s = 0; s < 2; ++s) \
          acc[m+4][n+2] = mfma16(aH[m][s], bH[n][s], acc[m+4][n+2]); \
    __builtin_amdgcn_s_setprio(0); \
    STAGE_A(C, tn2, 0); \
    __builtin_amdgcn_s_setprio(1); \
    _Pragma("unroll") for (int m = 0; m < 4; ++m) \
      _Pragma("unroll") for (int n = 0; n < 2; ++n) \
        _Pragma("unroll") for (int s = 0; s < 2; ++s) \
          acc[m+4][n] = mfma16(aH[m][s], bL[n][s], acc[m+4][n]); \
    __builtin_amdgcn_s_setprio(0); \
    VMCNT2(); \
    BAR(); \
  } while (0)

  STAGE_A(0, 0, 0); STAGE_A(0, 0, 1); STAGE_B(0, 0, 0); STAGE_B(0, 0, 1);
  STAGE_A(1, 1, 0);
  VMCNT2();
  BAR();

  for (int i = 0; i < NT / 2; ++i) {
    int t0 = 2 * i;
    int n1 = t0 + 2; if (n1 > NT - 1) n1 = NT - 1;
    int n2 = t0 + 3; if (n2 > NT - 1) n2 = NT - 1;
    GROUP(0, t0 + 1, n1);
    GROUP(1, n1, n2);
  }
  VMCNT0();

  int r0 = bm * 256 + wr * 128 + ((lane >> 4) << 2);
  int c0 = bn * 256 + wc * 64 + (lane & 15);
  bool isqkv = (bn * 256) < QKVW;
#pragma unroll
  for (int m = 0; m < 8; ++m) {
#pragma unroll
    for (int n = 0; n < 4; ++n) {
      int col = c0 + n * 16;
      float bias = b1[col];
#pragma unroll
      for (int j = 0; j < 4; ++j) {
        int row = r0 + m * 16 + j;
        float v = acc[m][n][j] + bias;
        if (isqkv) {
          qkv[(size_t)row * QKVW + col] = f2bf(v);
        } else {
          float u = 0.7978845608f * (v + 0.044715f * v * v * v);
          float g = v / (1.f + __expf(-2.f * u));
          amlp[(size_t)row * N2CAT + (col - 6144)] = f2bf(g);
        }
      }
    }
  }
#undef STAGE_A
#undef STAGE_B
#undef RD
#undef GROUP
}

// ===== GEMM2 (R12 verbatim): 256x128, BK=64, 3-ring, 4-bar =====
__global__ __launch_bounds__(512, 2) void k_gemm2(const unsigned short* __restrict__ amlp,
    const unsigned short* __restrict__ w2b, const float* __restrict__ b2,
    const float* __restrict__ img, const float* __restrict__ txt,
    const float* __restrict__ gate, float* __restrict__ out) {
  __shared__ unsigned short As[3][256 * 64];
  __shared__ unsigned short Bs[3][128 * 64];
  const int K = N2CAT;        // 15360
  const int NT = K / 64;      // 240 K-tiles
  int tid = threadIdx.x, lane = tid & 63, wid = tid >> 6;
  int wr = wid >> 1, wc = wid & 1;

  int b = blockIdx.x;                       // 216 % 8 == 0
  int bsw = (b & 7) * 27 + (b >> 3);
  int bm = bsw % 9, bn = bsw / 9;

  const unsigned short* Ag = amlp + (size_t)bm * 256 * K;
  const unsigned short* Bg = w2b + (size_t)bn * 128 * K;

  int sgran = (lane & 7) ^ ((lane >> 3) & 7);
  int srow = wid * 16 + (lane >> 3);

#define STAGE2_A(bufi, t, hh) do { \
    gload16(Ag + (size_t)((hh)*128 + srow) * K + (t)*64 + sgran*8, \
            &As[bufi][((hh)*128 + wid*16) * 64]); \
    gload16(Ag + (size_t)((hh)*128 + 8 + srow) * K + (t)*64 + sgran*8, \
            &As[bufi][((hh)*128 + wid*16 + 8) * 64]); \
  } while (0)
#define STAGE2_B(bufi, t) do { \
    gload16(Bg + (size_t)(srow) * K + (t)*64 + sgran*8, \
            &Bs[bufi][(wid*16) * 64]); \
    gload16(Bg + (size_t)(8 + srow) * K + (t)*64 + sgran*8, \
            &Bs[bufi][(wid*16 + 8) * 64]); \
  } while (0)

  int rA = wr * 64 + (lane & 15);
  int rB = wc * 64 + (lane & 15);
  int qq = lane >> 4, l7 = lane & 7;

  f4 acc[4][4];
#pragma unroll
  for (int m = 0; m < 4; ++m)
#pragma unroll
    for (int n = 0; n < 4; ++n) acc[m][n] = (f4){0.f, 0.f, 0.f, 0.f};
  bf8 aL[2][2], aH[2][2], bL[2][2], bH[2][2];

#define RD2(buf, r, s) (*(const bf8*)&buf[(r) * 64 + ((((s)*4 + qq) ^ l7) << 3)])

#define GROUP2(C, SB, t, full) do { \
    _Pragma("unroll") for (int m = 0; m < 2; ++m) \
      _Pragma("unroll") for (int s = 0; s < 2; ++s) aL[m][s] = RD2(As[C], rA + m*16, s); \
    _Pragma("unroll") for (int n = 0; n < 2; ++n) \
      _Pragma("unroll") for (int s = 0; s < 2; ++s) bL[n][s] = RD2(Bs[C], rB + n*16, s); \
    if (full) STAGE2_A(SB, (t) + 2, 0); \
    LGKM0(); \
    __builtin_amdgcn_s_setprio(1); \
    _Pragma("unroll") for (int m = 0; m < 2; ++m) \
      _Pragma("unroll") for (int n = 0; n < 2; ++n) \
        _Pragma("unroll") for (int s = 0; s < 2; ++s) \
          acc[m][n] = mfma16(aL[m][s], bL[n][s], acc[m][n]); \
    __builtin_amdgcn_s_setprio(0); \
    BAR(); \
    _Pragma("unroll") for (int n = 0; n < 2; ++n) \
      _Pragma("unroll") for (int s = 0; s < 2; ++s) bH[n][s] = RD2(Bs[C], rB + (n+2)*16, s); \
    if (full) STAGE2_A(SB, (t) + 2, 1); \
    LGKM0(); \
    __builtin_amdgcn_s_setprio(1); \
    _Pragma("unroll") for (int m = 0; m < 2; ++m) \
      _Pragma("unroll") for (int n = 0; n < 2; ++n) \
        _Pragma("unroll") for (int s = 0; s < 2; ++s) \
          acc[m][n+2] = mfma16(aL[m][s], bH[n][s], acc[m][n+2]); \
    __builtin_amdgcn_s_setprio(0); \
    BAR(); \
    _Pragma("unroll") for (int m = 0; m < 2; ++m) \
      _Pragma("unroll") for (int s = 0; s < 2; ++s) aH[m][s] = RD2(As[C], rA + (m+2)*16, s); \
    if (full) STAGE2_B(SB, (t) + 2); \
    LGKM0(); \
    __builtin_amdgcn_s_setprio(1); \
    _Pragma("unroll") for (int m = 0; m < 2; ++m) \
      _Pragma("unroll") for (int n = 0; n < 2; ++n) \
        _Pragma("unroll") for (int s = 0; s < 2; ++s) \
          acc[m+2][n+2] = mfma16(aH[m][s], bH[n][s], acc[m+2][n+2]); \
    __builtin_amdgcn_s_setprio(0); \
    BAR(); \
    __builtin_amdgcn_s_setprio(1); \
    _Pragma("unroll") for (int m = 0; m < 2; ++m) \
      _Pragma("unroll") for (int n = 0; n < 2; ++n) \
        _Pragma("unroll") for (int s = 0; s < 2; ++s) \
          acc[m+2][n] = mfma16(aH[m][s], bL[n][s], acc[m+2][n]); \
    __builtin_amdgcn_s_setprio(0); \
    if (full) { VMCNT6(); } else { VMCNT0(); } \
    BAR(); \
  } while (0)

  STAGE2_A(0, 0, 0); STAGE2_A(0, 0, 1); STAGE2_B(0, 0);
  STAGE2_A(1, 1, 0); STAGE2_A(1, 1, 1); STAGE2_B(1, 1);
  VMCNT6();
  BAR();

  for (int i = 0; i < NT / 3; ++i) {
    int t = 3 * i;
    GROUP2(0, 2, t,     (t + 2) < NT);
    GROUP2(1, 0, t + 1, (t + 3) < NT);
    GROUP2(2, 1, t + 2, (t + 4) < NT);
  }
  VMCNT0();

  int r0 = bm * 256 + wr * 64 + ((lane >> 4) << 2);
  int c0 = bn * 128 + wc * 64 + (lane & 15);
#pragma unroll
  for (int m = 0; m < 4; ++m) {
#pragma unroll
    for (int n = 0; n < 4; ++n) {
      int col = c0 + n * 16;
      float bias = b2[col];
      float gt = gate[col];
#pragma unroll
      for (int j = 0; j < 4; ++j) {
        int row = r0 + m * 16 + j;
        float v = acc[m][n][j] + bias;
        float res = (row < LI) ? img[(size_t)row * HID + col]
                               : txt[(size_t)(row - LI) * HID + col];
        out[(size_t)row * HID + col] = res + gt * v;
      }
    }
  }
#undef STAGE2_A
#undef STAGE2_B
#undef RD2
#undef GROUP2
}

// ---- fused qknorm (blocks 0..13823) + V-transpose (blocks 13824..15551) ----
__global__ void k_qkvt(unsigned short* __restrict__ qkv, const float* __restrict__ qw,
                       const float* __restrict__ kw, const float* __restrict__ fcos,
                       const float* __restrict__ fsin, unsigned short* __restrict__ vt) {
  int b = blockIdx.x;
  int tid = threadIdx.x;
  __shared__ unsigned short tile[64 * 65];
  if (b < 13824) {
    int gw = (b * 256 + tid) >> 6;
    int lane = tid & 63;
    int token = gw / NHEAD, head = gw - token * NHEAD;
    bool dorope = token < LI;
    float c = 1.f, sn = 0.f;
    if (dorope) { c = fcos[token * HD + 2 * lane]; sn = fsin[token * HD + 2 * lane]; }
#pragma unroll
    for (int qk = 0; qk < 2; ++qk) {
      unsigned short* p = qkv + (size_t)token * QKVW + qk * HID + head * HD;
      unsigned u = ((const unsigned*)p)[lane];
      float x0 = bf2f((unsigned short)(u & 0xffff));
      float x1 = bf2f((unsigned short)(u >> 16));
      float ss = x0 * x0 + x1 * x1;
#pragma unroll
      for (int m2 = 32; m2; m2 >>= 1) ss += __shfl_xor(ss, m2);
      float inv = rsqrtf(ss * (1.f / HD) + 1e-6f);
      const float* w = qk ? kw : qw;
      float y0 = x0 * inv * w[2 * lane];
      float y1 = x1 * inv * w[2 * lane + 1];
      if (dorope) { float r0 = y0 * c - y1 * sn; float r1 = y1 * c + y0 * sn; y0 = r0; y1 = r1; }
      ((unsigned*)p)[lane] = ((unsigned)f2bf(y0)) | (((unsigned)f2bf(y1)) << 16);
    }
  } else {
    int bb = b - 13824;                 // 24*36*2
    int h = bb / 72; int rem = bb - h * 72; int tt = rem >> 1; int dd = rem & 1;
    int t0 = tt * 64, d0 = dd * 64;
#pragma unroll
    for (int j = 0; j < 2; ++j) {
      int idx = j * 256 + tid;
      int row = idx >> 3, s = idx & 7;
      us8 vv = *(const us8*)(qkv + (size_t)(t0 + row) * QKVW + 2 * HID + h * HD + d0 + s * 8);
#pragma unroll
      for (int i = 0; i < 8; ++i) tile[row * 65 + s * 8 + i] = vv[i];
    }
    __syncthreads();
#pragma unroll
    for (int j = 0; j < 2; ++j) {
      int idx = j * 256 + tid;
      int dr = idx >> 3, sl = idx & 7;
      us8 o;
#pragma unroll
      for (int i = 0; i < 8; ++i) o[i] = tile[(sl * 8 + i) * 65 + dr];
      *(us8*)(vt + (size_t)(h * HD + d0 + dr) * SEQ + t0 + sl * 8) = o;
    }
  }
}

// ===== flash attention v3 (R12 verbatim): QBLK=128, 8 waves, K/V dbuf, Q-frags global =====
__global__ __launch_bounds__(512, 4) void k_attn(const unsigned short* __restrict__ qkv,
                                                 const unsigned short* __restrict__ vt,
                                                 unsigned short* __restrict__ amlp,
                                                 const float* __restrict__ w2,
                                                 unsigned short* __restrict__ w2b) {
  int b = blockIdx.x;
  int tid = threadIdx.x;
  if (b >= 432) {           // w2 converter blocks
    int cb = b - 432;
    const int n4 = HID * N2CAT / 4;
    for (int i = cb * 512 + tid; i < n4; i += 768 * 512) {
      float4 f = ((const float4*)w2)[i];
      ushort4 o;
      o.x = f2bf(f.x); o.y = f2bf(f.y); o.z = f2bf(f.z); o.w = f2bf(f.w);
      ((ushort4*)w2b)[i] = o;
    }
    return;
  }
  __shared__ unsigned short S[40960];   // 80 KB
  unsigned short* Ks = S;               // 2 x 8192 (64x128)
  unsigned short* Vs = S + 16384;       // 2 x 8192 (128x64)
  unsigned short* Ps = S + 32768;       // 128 x 64

  int bsw = (b & 7) * 54 + (b >> 3);    // 432 = 54*8
  int head = bsw / 18, qt = bsw - head * 18;
  int lane = tid & 63, wv = tid >> 6;
  int qbase = qt * 128;

#define STAGEK(dst, t) do { \
    int rl_ = tid >> 4, sl_ = tid & 15, sg_ = sl_ ^ (rl_ & 7); \
    const unsigned short* kg_ = qkv + HID + (size_t)((t) * 64 + rl_) * QKVW + head * HD + sg_ * 8; \
    gload16(kg_, &(dst)[tid * 8]); \
    gload16(kg_ + (size_t)32 * QKVW, &(dst)[(512 + tid) * 8]); \
  } while (0)
#define STAGEV(dst, t) do { \
    int rl_ = tid >> 3, sl_ = tid & 7, sg_ = sl_ ^ (rl_ & 7); \
    const unsigned short* vg_ = vt + (size_t)(head * HD + rl_) * SEQ + (t) * 64 + sg_ * 8; \
    gload16(vg_, &(dst)[tid * 8]); \
    gload16(vg_ + (size_t)64 * SEQ, &(dst)[(512 + tid) * 8]); \
  } while (0)

  bf8 qf[4];
  {
    const unsigned short* qp =
        qkv + (size_t)(qbase + wv * 16 + (lane & 15)) * QKVW + head * HD + (lane >> 4) * 8;
#pragma unroll
    for (int kk = 0; kk < 4; ++kk) qf[kk] = *(const bf8*)(qp + kk * 32);
  }
  STAGEK(Ks, 0); STAGEV(Vs, 0);
  STAGEK(Ks + 8192, 1); STAGEV(Vs + 8192, 1);
  VMCNT4();
  BAR();

  float mrun[4], lrun[4];
  f4 oacc[8];
#pragma unroll
  for (int j = 0; j < 4; ++j) { mrun[j] = -1e30f; lrun[j] = 0.f; }
#pragma unroll
  for (int n = 0; n < 8; ++n) oacc[n] = (f4){0.f, 0.f, 0.f, 0.f};

  for (int kt = 0; kt < SEQ / 64; ++kt) {
    int cur = kt & 1;
    const unsigned short* Kc = Ks + cur * 8192;
    const unsigned short* Vc = Vs + cur * 8192;
    f4 sacc[4];
#pragma unroll
    for (int n = 0; n < 4; ++n) sacc[n] = (f4){0.f, 0.f, 0.f, 0.f};
#pragma unroll
    for (int kk = 0; kk < 4; ++kk) {
#pragma unroll
      for (int n = 0; n < 4; ++n) {
        int row = n * 16 + (lane & 15);
        int col = (kk * 32 + ((lane >> 4) * 8)) ^ ((lane & 7) << 3);
        bf8 kf = *(const bf8*)&Kc[row * 128 + col];
        sacc[n] = mfma16(qf[kk], kf, sacc[n]);
      }
    }
    const float SC = 0.08838834764831845f;
    float mj[4];
#pragma unroll
    for (int j = 0; j < 4; ++j)
      mj[j] = fmaxf(fmaxf(sacc[0][j], sacc[1][j]), fmaxf(sacc[2][j], sacc[3][j]));
#pragma unroll
    for (int j = 0; j < 4; ++j) {
#pragma unroll
      for (int mk = 8; mk; mk >>= 1) mj[j] = fmaxf(mj[j], __shfl_xor(mj[j], mk));
    }
    float resc[4], psum[4];
#pragma unroll
    for (int j = 0; j < 4; ++j) {
      float nm = fmaxf(mrun[j], mj[j] * SC);
      resc[j] = __expf(mrun[j] - nm);
      mrun[j] = nm;
      psum[j] = 0.f;
    }
#pragma unroll
    for (int n = 0; n < 4; ++n) {
#pragma unroll
      for (int j = 0; j < 4; ++j) {
        float p = __expf(sacc[n][j] * SC - mrun[j]);
        psum[j] += p;
        int row = wv * 16 + ((lane >> 4) << 2) + j;
        int col = (n * 16 + (lane & 15)) ^ ((row & 7) << 3);
        Ps[row * 64 + col] = f2bf(p);
      }
    }
#pragma unroll
    for (int j = 0; j < 4; ++j) {
#pragma unroll
      for (int mk = 8; mk; mk >>= 1) psum[j] += __shfl_xor(psum[j], mk);
      lrun[j] = lrun[j] * resc[j] + psum[j];
    }
#pragma unroll
    for (int n = 0; n < 8; ++n) {
#pragma unroll
      for (int j = 0; j < 4; ++j) oacc[n][j] *= resc[j];
    }
#pragma unroll
    for (int kk = 0; kk < 2; ++kk) {
      int prow = wv * 16 + (lane & 15);
      int pcol = (kk * 32 + ((lane >> 4) * 8)) ^ ((lane & 7) << 3);
      bf8 pa = *(const bf8*)&Ps[prow * 64 + pcol];
#pragma unroll
      for (int n = 0; n < 8; ++n) {
        int vrow = n * 16 + (lane & 15);
        int vcol = (kk * 32 + ((lane >> 4) * 8)) ^ ((vrow & 7) << 3);
        bf8 vf = *(const bf8*)&Vc[vrow * 64 + vcol];
        oacc[n] = mfma16(pa, vf, oacc[n]);
      }
    }
    BAR();
    if (kt + 2 < SEQ / 64) {
      STAGEK(Ks + cur * 8192, kt + 2);
      STAGEV(Vs + cur * 8192, kt + 2);
      VMCNT4();
    } else {
      VMCNT0();
    }
    BAR();
  }
#undef STAGEK
#undef STAGEV

#pragma unroll
  for (int j = 0; j < 4; ++j) {
    float invl = 1.f / lrun[j];
    int row = qbase + wv * 16 + ((lane >> 4) << 2) + j;
#pragma unroll
    for (int n = 0; n < 8; ++n) {
      int col = head * HD + n * 16 + (lane & 15);
      amlp[(size_t)row * N2CAT + col] = f2bf(oacc[n][j] * invl);
    }
  }
}

extern "C" void kernel_launch(void* const* d_in, const int* in_sizes, int n_in,
                              void* d_out, int out_size, void* d_ws, size_t ws_size,
                              hipStream_t stream) {
  (void)in_sizes; (void)n_in; (void)out_size; (void)ws_size;
  const float* img  = (const float*)d_in[0];
  const float* txt  = (const float*)d_in[1];
  const float* vec  = (const float*)d_in[2];
  const float* fcos = (const float*)d_in[3];
  const float* fsin = (const float*)d_in[4];
  const float* w1   = (const float*)d_in[5];
  const float* b1   = (const float*)d_in[6];
  const float* w2   = (const float*)d_in[7];
  const float* b2   = (const float*)d_in[8];
  const float* qnw  = (const float*)d_in[9];
  const float* knw  = (const float*)d_in[10];
  const float* mw   = (const float*)d_in[11];
  const float* mb   = (const float*)d_in[12];
  float* out = (float*)d_out;

  char* ws = (char*)d_ws;
  float*          mod  = (float*)(ws);                          // 36,864 B
  unsigned short* xmod = (unsigned short*)(ws + 40960);         // 14,155,776 B
  unsigned short* w1b  = (unsigned short*)(ws + 14196736);      // 132,120,576 B
  unsigned short* qkv  = (unsigned short*)(ws + 146317312);     // 42,467,328 B
  unsigned short* amlp = (unsigned short*)(ws + 188784640);     // 70,778,880 B (end ~259.6MB)
  unsigned short* vtb  = xmod;   // x_mod dead after GEMM1
  unsigned short* w2b  = w1b;    // w1 bf16 dead after GEMM1 (w2 converted inside k_attn)

  k_mod<<<QKVW / 4, 256, 0, stream>>>(vec, mw, mb, mod);
  k_lnmod<<<SEQ + 1024, 256, 0, stream>>>(img, txt, mod, xmod, w1, w1b);
  k_gemm1<<<756, 512, 0, stream>>>(xmod, w1b, b1, qkv, amlp);
  k_qkvt<<<13824 + 1728, 256, 0, stream>>>(qkv, qnw, knw, fcos, fsin, vtb);
  k_attn<<<432 + 768, 512, 0, stream>>>(qkv, vtb, amlp, w2, w2b);
  k_gemm2<<<216, 512, 0, stream>>>(amlp, w2b, b2, img, txt, mod + 2 * HID, out);
}